// Round 1
// baseline (792.013 us; speedup 1.0000x reference)
//
#include <hip/hip_runtime.h>

typedef __attribute__((ext_vector_type(8))) short bf8;
typedef __attribute__((ext_vector_type(4))) float f4;

#define MFMA16(A,B,C) __builtin_amdgcn_mfma_f32_16x16x32_bf16(A,B,C,0,0,0)

#define NTOK 98
#define SROW 136
#define SCALE 0.17677669529663687f

__device__ __forceinline__ unsigned short bfu(float f) {
  union { float f; unsigned u; } un; un.f = f;
  unsigned r = un.u + 0x7FFFu + ((un.u >> 16) & 1u);
  return (unsigned short)(r >> 16);
}

__global__ void prep_kernel(const float* __restrict__ qkv_w,
                            const float* __restrict__ proj_w,
                            const float* __restrict__ bias_table,
                            const int* __restrict__ rel_index,
                            unsigned short* __restrict__ wq,
                            unsigned short* __restrict__ wp,
                            float* __restrict__ biasT) {
  int idx = blockIdx.x * blockDim.x + threadIdx.x;
  const int T1 = 384*128;          // qkv_w elems
  const int T2 = T1 + 128*128;     // + proj_w elems
  const int T3 = T2 + 4*9604;      // + bias[h][n][m]
  for (; idx < T3; idx += gridDim.x * blockDim.x) {
    if (idx < T1)       wq[idx] = bfu(qkv_w[idx]);
    else if (idx < T2)  wp[idx - T1] = bfu(proj_w[idx - T1]);
    else {
      int t = idx - T2;
      int h = t / 9604, r = t % 9604;
      biasT[t] = bias_table[rel_index[r]*4 + h];
    }
  }
}

__launch_bounds__(512, 2)
__global__ void wattn_kernel(const float* __restrict__ x,
                             const float* __restrict__ mask,
                             const float* __restrict__ proj_b,
                             const unsigned short* __restrict__ wqkv,
                             const unsigned short* __restrict__ wproj,
                             const float* __restrict__ biasT,
                             float* __restrict__ out) {
  // LDS: total 161,024 B (<160 KiB). Row stride 136 elems = 272 B:
  // 16B-aligned for ds_read_b128, stride-272B -> only 2-way bank conflict (free).
  __shared__ unsigned short xb[112*SROW];      // x bf16, reused as attention-out
  __shared__ unsigned short qb[112*SROW];      // q (pre-scaled) [n][h*32+d]
  __shared__ unsigned short kb[112*SROW];      // k [m][h*32+d]
  __shared__ unsigned short vt[128*SROW];      // V^T [h*32+d][m]
  __shared__ unsigned short tp[8][16*SROW];    // per-wave P transpose scratch

  const int b   = blockIdx.x;
  const int tid = threadIdx.x;
  const int wid = tid >> 6;
  const int lane = tid & 63;
  const int g = lane >> 4;        // 16-lane group 0..3
  const int c = lane & 15;

  // ---- init: zero padding rows/cols so garbage never reaches MFMA ----
  for (int i = tid; i < 14*SROW; i += 512) xb[98*SROW + i] = 0;            // x rows 98..111
  for (int i = tid; i < 128*24; i += 512) {                                 // Vt cols 112..135
    int r = i / 24, cc = 112 + (i % 24);
    vt[r*SROW + cc] = 0;
  }
  for (int i = tid; i < 8*16*SROW; i += 512) ((unsigned short*)tp)[i] = 0;  // P scratch

  // ---- load x -> LDS bf16 (coalesced float4) ----
  const float* xp = x + (size_t)b * (NTOK*128);
  for (int i = tid; i < (NTOK*128)/4; i += 512) {
    float4 v4 = ((const float4*)xp)[i];
    int e = i * 4;
    int n = e >> 7, cc = e & 127;
    unsigned short* dst = &xb[n*SROW + cc];
    dst[0] = bfu(v4.x); dst[1] = bfu(v4.y); dst[2] = bfu(v4.z); dst[3] = bfu(v4.w);
  }
  __syncthreads();

  // ---- QKV GEMM: (112x128) @ Wqkv^T(384x128) -> q/k/Vt in LDS ----
  for (int ot = wid; ot < 24; ot += 8) {
    f4 acc[7] = {};
    #pragma unroll
    for (int kk = 0; kk < 4; ++kk) {
      bf8 bfrag = *(const bf8*)(wqkv + ((ot*16 + c)*128 + kk*32 + g*8));
      #pragma unroll
      for (int i = 0; i < 7; ++i) {
        bf8 afrag = *(const bf8*)(&xb[(i*16 + c)*SROW + kk*32 + g*8]);
        acc[i] = MFMA16(afrag, bfrag, acc[i]);
      }
    }
    int o = ot*16 + c;   // 0..383, region uniform per ot
    #pragma unroll
    for (int i = 0; i < 7; ++i) {
      int nb = i*16 + g*4;
      #pragma unroll
      for (int r = 0; r < 4; ++r) {
        float v = acc[i][r];
        int n = nb + r;
        if (o < 128)      qb[n*SROW + o] = bfu(v * SCALE);
        else if (o < 256) kb[n*SROW + (o-128)] = bfu(v);
        else              vt[(o-256)*SROW + n] = bfu(v);
      }
    }
  }
  __syncthreads();

  // ---- attention: 2 waves per head, split over row-tiles ----
  {
    const int h = wid >> 1, half = wid & 1;
    const int i0 = half ? 4 : 0, i1 = half ? 7 : 4;
    const int w = b & 63;
    const float* mw = mask  + (size_t)w * 9604;
    const float* bh = biasT + (size_t)h * 9604;
    unsigned short* myp = tp[wid];

    for (int i = i0; i < i1; ++i) {
      // S row-block 16x112: 7 MFMAs
      f4 s[7];
      bf8 qf = *(const bf8*)(&qb[(i*16 + c)*SROW + h*32 + g*8]);
      #pragma unroll
      for (int j = 0; j < 7; ++j) {
        bf8 kf = *(const bf8*)(&kb[(j*16 + c)*SROW + h*32 + g*8]);
        f4 z = {0.f, 0.f, 0.f, 0.f};
        s[j] = MFMA16(qf, kf, z);
      }
      // softmax per row (row n held by 16-lane group, reg r; cols = 16j+c)
      #pragma unroll
      for (int r = 0; r < 4; ++r) {
        int n = i*16 + g*4 + r;
        bool nv = n < NTOK;
        float sv[7];
        #pragma unroll
        for (int j = 0; j < 7; ++j) {
          int m = j*16 + c;
          float val = -1e30f;
          if (nv && m < NTOK) val = s[j][r] + bh[n*98 + m] + mw[n*98 + m];
          sv[j] = val;
        }
        float mx = sv[0];
        #pragma unroll
        for (int j = 1; j < 7; ++j) mx = fmaxf(mx, sv[j]);
        mx = fmaxf(mx, __shfl_xor(mx, 1));
        mx = fmaxf(mx, __shfl_xor(mx, 2));
        mx = fmaxf(mx, __shfl_xor(mx, 4));
        mx = fmaxf(mx, __shfl_xor(mx, 8));
        float p[7]; float sum = 0.f;
        #pragma unroll
        for (int j = 0; j < 7; ++j) { p[j] = __expf(sv[j] - mx); sum += p[j]; }
        sum += __shfl_xor(sum, 1);
        sum += __shfl_xor(sum, 2);
        sum += __shfl_xor(sum, 4);
        sum += __shfl_xor(sum, 8);
        float inv = 1.f / sum;
        #pragma unroll
        for (int j = 0; j < 7; ++j)
          myp[(g*4 + r)*SROW + j*16 + c] = bfu(p[j] * inv);   // transpose to A-layout
      }
      asm volatile("s_waitcnt lgkmcnt(0)" ::: "memory");  // own-wave ds_write -> ds_read
      // PV: out_block(16x32) = P(16x128) @ V(128x32)
      #pragma unroll
      for (int ot2 = 0; ot2 < 2; ++ot2) {
        f4 acc = {0.f, 0.f, 0.f, 0.f};
        #pragma unroll
        for (int kk = 0; kk < 4; ++kk) {
          bf8 pa = *(const bf8*)(&myp[c*SROW + kk*32 + g*8]);
          bf8 vb = *(const bf8*)(&vt[(h*32 + ot2*16 + c)*SROW + kk*32 + g*8]);
          acc = MFMA16(pa, vb, acc);
        }
        #pragma unroll
        for (int r = 0; r < 4; ++r) {
          int n = i*16 + g*4 + r;
          xb[n*SROW + h*32 + ot2*16 + c] = bfu(acc[r]);   // xb reused as attn-out
        }
      }
    }
  }
  __syncthreads();

  // ---- proj: (112x128) @ Wproj^T(128x128) + b -> global fp32 ----
  for (int idx = wid; idx < 56; idx += 8) {
    int i = idx >> 3, ot = idx & 7;
    f4 acc = {0.f, 0.f, 0.f, 0.f};
    #pragma unroll
    for (int kk = 0; kk < 4; ++kk) {
      bf8 a  = *(const bf8*)(&xb[(i*16 + c)*SROW + kk*32 + g*8]);
      bf8 bw = *(const bf8*)(wproj + ((ot*16 + c)*128 + kk*32 + g*8));
      acc = MFMA16(a, bw, acc);
    }
    int o = ot*16 + c;
    float pb = proj_b[o];
    #pragma unroll
    for (int r = 0; r < 4; ++r) {
      int n = i*16 + g*4 + r;
      if (n < NTOK)
        out[(size_t)b*(NTOK*128) + n*128 + o] = acc[r] + pb;
    }
  }
}

extern "C" void kernel_launch(void* const* d_in, const int* in_sizes, int n_in,
                              void* d_out, int out_size, void* d_ws, size_t ws_size,
                              hipStream_t stream) {
  const float* x          = (const float*)d_in[0];
  const float* mask       = (const float*)d_in[1];
  const float* qkv_w      = (const float*)d_in[2];
  const float* proj_w     = (const float*)d_in[3];
  const float* proj_b     = (const float*)d_in[4];
  const float* bias_table = (const float*)d_in[5];
  const int*   rel_index  = (const int*)d_in[6];

  // workspace layout: wqkv bf16 (98,304 B) | wproj bf16 (32,768 B) | biasT fp32 (153,664 B)
  unsigned short* wq = (unsigned short*)d_ws;
  unsigned short* wp = wq + 384*128;
  float* biasT = (float*)(wq + 384*128 + 128*128);

  prep_kernel<<<256, 256, 0, stream>>>(qkv_w, proj_w, bias_table, rel_index, wq, wp, biasT);
  wattn_kernel<<<4096, 512, 0, stream>>>(x, mask, proj_b, wq, wp, biasT, (float*)d_out);
}

// Round 2
// 334.828 us; speedup vs baseline: 2.3654x; 2.3654x over previous
//
#include <hip/hip_runtime.h>

typedef __attribute__((ext_vector_type(8))) short bf8;
typedef __attribute__((ext_vector_type(4))) float f4;

#define MFMA16(A,B,C) __builtin_amdgcn_mfma_f32_16x16x32_bf16(A,B,C,0,0,0)

#define NTOK 98
#define SROW 136
#define SCALE 0.17677669529663687f

__device__ __forceinline__ unsigned short bfu(float f) {
  union { float f; unsigned u; } un; un.f = f;
  unsigned r = un.u + 0x7FFFu + ((un.u >> 16) & 1u);
  return (unsigned short)(r >> 16);
}

// prep: bf16 weights + fused bias+mask table (path A) or bias-only table (path B)
__global__ void prep_kernel(const float* __restrict__ qkv_w,
                            const float* __restrict__ proj_w,
                            const float* __restrict__ bias_table,
                            const int* __restrict__ rel_index,
                            const float* __restrict__ mask,
                            unsigned short* __restrict__ wq,
                            unsigned short* __restrict__ wp,
                            float* __restrict__ bm,
                            int use_bm) {
  const int T1 = 384*128;
  const int T2 = T1 + 128*128;
  const int total = T2 + (use_bm ? 64*4*112*112 : 4*9604);
  for (int idx = blockIdx.x * blockDim.x + threadIdx.x; idx < total;
       idx += gridDim.x * blockDim.x) {
    if (idx < T1)       wq[idx] = bfu(qkv_w[idx]);
    else if (idx < T2)  wp[idx - T1] = bfu(proj_w[idx - T1]);
    else if (use_bm) {
      int t = idx - T2;
      int m = t % 112; int t2 = t / 112;
      int n = t2 % 112; int t3 = t2 / 112;
      int h = t3 & 3;  int w = t3 >> 2;
      float v;
      if (m >= NTOK)      v = -1e30f;
      else if (n >= NTOK) v = 0.f;
      else v = bias_table[rel_index[n*98 + m]*4 + h] + mask[(size_t)w*9604 + n*98 + m];
      bm[t] = v;
    } else {
      int t = idx - T2;
      int h = t / 9604, r = t % 9604;
      bm[t] = bias_table[rel_index[r]*4 + h];
    }
  }
}

template<int USE_BM>
__launch_bounds__(512, 2)
__global__ void wattn_kernel(const float* __restrict__ x,
                             const float* __restrict__ mask,
                             const float* __restrict__ proj_b,
                             const unsigned short* __restrict__ wqkv,
                             const unsigned short* __restrict__ wproj,
                             const float* __restrict__ bm,
                             float* __restrict__ out) {
  // 161,024 B LDS. SROW=136 elems (272 B): 16B-aligned rows.
  __shared__ unsigned short xb[112*SROW];      // x bf16, reused as attention-out [n][d]
  __shared__ unsigned short qb[112*SROW];      // q (pre-scaled) [n][d]
  __shared__ unsigned short kb[112*SROW];      // k [m][d]
  __shared__ unsigned short vt[128*SROW];      // V^T [d][m]
  __shared__ unsigned short tp[8][16*SROW];    // per-wave P [n][m] scratch

  const int b = blockIdx.x, tid = threadIdx.x;
  const int wid = tid >> 6, lane = tid & 63;
  const int g = lane >> 4, c = lane & 15;

  // zero padding regions
  for (int i = tid; i < 14*SROW; i += 512) xb[98*SROW + i] = 0;       // x rows 98..111
  for (int i = tid; i < 128*24; i += 512) {                            // Vt cols 112..135
    int r = i / 24, cc = 112 + (i % 24);
    vt[r*SROW + cc] = 0;
  }
  for (int i = tid; i < 8*16*SROW; i += 512) ((unsigned short*)tp)[i] = 0;

  // ---- load x -> LDS bf16 (float4 in, ushort4 packed LDS write) ----
  const float* xp = x + (size_t)b * (NTOK*128);
  for (int i = tid; i < (NTOK*128)/4; i += 512) {
    float4 v4 = ((const float4*)xp)[i];
    int e = i * 4, n = e >> 7, cc = e & 127;
    ushort4 u;
    u.x = bfu(v4.x); u.y = bfu(v4.y); u.z = bfu(v4.z); u.w = bfu(v4.w);
    *(ushort4*)&xb[n*SROW + cc] = u;
  }
  __syncthreads();

  // ---- QKV: wave wid owns q-tile wid (swapped), k-tile wid (swapped), v-tile wid ----
  {
    const unsigned short* wq_p = wqkv + (      wid*16 + c)*128;
    const unsigned short* wk_p = wqkv + (128 + wid*16 + c)*128;
    const unsigned short* wv_p = wqkv + (256 + wid*16 + c)*128;
    f4 aq[7] = {}, ak[7] = {}, av[7] = {};
    #pragma unroll
    for (int kk = 0; kk < 4; ++kk) {
      bf8 wqf = *(const bf8*)(wq_p + kk*32 + g*8);
      bf8 wkf = *(const bf8*)(wk_p + kk*32 + g*8);
      bf8 wvf = *(const bf8*)(wv_p + kk*32 + g*8);
      #pragma unroll
      for (int i = 0; i < 7; ++i) {
        bf8 xf = *(const bf8*)(&xb[(i*16 + c)*SROW + kk*32 + g*8]);
        aq[i] = MFMA16(wqf, xf, aq[i]);   // D[o'][n'] -> q^T fragment
        ak[i] = MFMA16(wkf, xf, ak[i]);   // D[o'][n'] -> k^T fragment
        av[i] = MFMA16(xf, wvf, av[i]);   // D[n'][o'] -> packs into Vt
      }
    }
    #pragma unroll
    for (int i = 0; i < 7; ++i) {
      ushort4 u;
      u.x = bfu(aq[i][0]*SCALE); u.y = bfu(aq[i][1]*SCALE);
      u.z = bfu(aq[i][2]*SCALE); u.w = bfu(aq[i][3]*SCALE);
      *(ushort4*)&qb[(i*16 + c)*SROW + wid*16 + g*4] = u;
      u.x = bfu(ak[i][0]); u.y = bfu(ak[i][1]); u.z = bfu(ak[i][2]); u.w = bfu(ak[i][3]);
      *(ushort4*)&kb[(i*16 + c)*SROW + wid*16 + g*4] = u;
      u.x = bfu(av[i][0]); u.y = bfu(av[i][1]); u.z = bfu(av[i][2]); u.w = bfu(av[i][3]);
      *(ushort4*)&vt[(wid*16 + c)*SROW + i*16 + g*4] = u;
    }
  }
  __syncthreads();

  // ---- attention: 2 waves/head; S^T formulation; bm as MFMA C-init ----
  {
    const int h = wid >> 1, half = wid & 1;
    const int i0 = half * 4, i1 = half ? 7 : 4;
    unsigned short* myp = tp[wid];
    const float* bmh = bm + (size_t)((b & 63)*4 + h) * (112*112);  // path A
    const float* bh  = bm + (size_t)h * 9604;                      // path B
    const float* mw  = mask + (size_t)(b & 63) * 9604;             // path B

    for (int i = i0; i < i1; ++i) {
      f4 s[7];
      if (USE_BM) {
        #pragma unroll
        for (int j = 0; j < 7; ++j)
          s[j] = *(const f4*)(bmh + (i*16 + c)*112 + j*16 + g*4);
      } else {
        #pragma unroll
        for (int j = 0; j < 7; ++j) s[j] = (f4){0.f,0.f,0.f,0.f};
      }
      bf8 qf = *(const bf8*)(&qb[(i*16 + c)*SROW + h*32 + g*8]);
      #pragma unroll
      for (int j = 0; j < 7; ++j) {
        bf8 kf = *(const bf8*)(&kb[(j*16 + c)*SROW + h*32 + g*8]);
        s[j] = MFMA16(kf, qf, s[j]);      // S^T[m'][n']: m=j*16+g*4+r, n=i*16+c
      }
      if (!USE_BM) {
        int n = i*16 + c;
        #pragma unroll
        for (int j = 0; j < 7; ++j)
          #pragma unroll
          for (int r = 0; r < 4; ++r) {
            int m = j*16 + g*4 + r;
            float v;
            if (m >= NTOK)      v = -1e30f;
            else if (n >= NTOK) v = 0.f;
            else                v = bh[n*98 + m] + mw[n*98 + m];
            s[j][r] += v;
          }
      }
      // softmax over m (values bounded ~12: skip max-sub; masked -> exp(-1e30)=0)
      float p[28];
      float sum = 0.f;
      #pragma unroll
      for (int j = 0; j < 7; ++j)
        #pragma unroll
        for (int r = 0; r < 4; ++r) { float e = __expf(s[j][r]); p[j*4+r] = e; sum += e; }
      sum += __shfl_xor(sum, 16);
      sum += __shfl_xor(sum, 32);
      float inv = 1.f / sum;
      #pragma unroll
      for (int j = 0; j < 7; ++j) {
        ushort4 u;
        u.x = bfu(p[j*4+0]*inv); u.y = bfu(p[j*4+1]*inv);
        u.z = bfu(p[j*4+2]*inv); u.w = bfu(p[j*4+3]*inv);
        *(ushort4*)&myp[c*SROW + j*16 + g*4] = u;   // P[n=c][m] packed
      }
      asm volatile("s_waitcnt lgkmcnt(0)" ::: "memory");  // own-wave ds_write -> ds_read
      #pragma unroll
      for (int ot2 = 0; ot2 < 2; ++ot2) {
        f4 acc = {0.f, 0.f, 0.f, 0.f};
        #pragma unroll
        for (int kk = 0; kk < 4; ++kk) {
          bf8 vf = *(const bf8*)(&vt[(h*32 + ot2*16 + c)*SROW + kk*32 + g*8]);
          bf8 pf = *(const bf8*)(&myp[c*SROW + kk*32 + g*8]);
          acc = MFMA16(vf, pf, acc);      // out^T[d'][n']
        }
        ushort4 u;
        u.x = bfu(acc[0]); u.y = bfu(acc[1]); u.z = bfu(acc[2]); u.w = bfu(acc[3]);
        *(ushort4*)&xb[(i*16 + c)*SROW + h*32 + ot2*16 + g*4] = u;
      }
    }
  }
  __syncthreads();

  // ---- proj (swapped): wave wid owns output col-tile wid; float4 stores ----
  {
    const unsigned short* wp_p = wproj + (wid*16 + c)*128;
    bf8 wf[4];
    #pragma unroll
    for (int kk = 0; kk < 4; ++kk) wf[kk] = *(const bf8*)(wp_p + kk*32 + g*8);
    f4 pb4 = *(const f4*)(proj_b + wid*16 + g*4);
    #pragma unroll
    for (int i = 0; i < 7; ++i) {
      f4 acc = {0.f, 0.f, 0.f, 0.f};
      #pragma unroll
      for (int kk = 0; kk < 4; ++kk) {
        bf8 xf = *(const bf8*)(&xb[(i*16 + c)*SROW + kk*32 + g*8]);
        acc = MFMA16(wf[kk], xf, acc);    // D[o'][n']
      }
      int n = i*16 + c;
      if (n < NTOK) {
        f4 o4 = {acc[0]+pb4[0], acc[1]+pb4[1], acc[2]+pb4[2], acc[3]+pb4[3]};
        *(f4*)(out + (size_t)b*(NTOK*128) + n*128 + wid*16 + g*4) = o4;
      }
    }
  }
}

extern "C" void kernel_launch(void* const* d_in, const int* in_sizes, int n_in,
                              void* d_out, int out_size, void* d_ws, size_t ws_size,
                              hipStream_t stream) {
  const float* x          = (const float*)d_in[0];
  const float* mask       = (const float*)d_in[1];
  const float* qkv_w      = (const float*)d_in[2];
  const float* proj_w     = (const float*)d_in[3];
  const float* proj_b     = (const float*)d_in[4];
  const float* bias_table = (const float*)d_in[5];
  const int*   rel_index  = (const int*)d_in[6];

  unsigned short* wq = (unsigned short*)d_ws;
  unsigned short* wp = wq + 384*128;
  float* bm = (float*)((char*)d_ws + 131072);

  const size_t needA = 131072u + (size_t)64*4*112*112*4;  // 12.98 MB
  const int use_bm = (ws_size >= needA) ? 1 : 0;

  prep_kernel<<<1024, 256, 0, stream>>>(qkv_w, proj_w, bias_table, rel_index, mask,
                                        wq, wp, bm, use_bm);
  if (use_bm)
    wattn_kernel<1><<<4096, 512, 0, stream>>>(x, mask, proj_b, wq, wp, bm, (float*)d_out);
  else
    wattn_kernel<0><<<4096, 512, 0, stream>>>(x, mask, proj_b, wq, wp, bm, (float*)d_out);
}

// Round 3
// 294.984 us; speedup vs baseline: 2.6849x; 1.1351x over previous
//
#include <hip/hip_runtime.h>

typedef __attribute__((ext_vector_type(8))) short bf8;
typedef __attribute__((ext_vector_type(4))) float f4;
typedef __attribute__((ext_vector_type(16))) float f16v;
typedef __attribute__((ext_vector_type(2))) unsigned int u32x2;
typedef __attribute__((ext_vector_type(4))) unsigned int u32x4;

#define MFMA16(A,B,C) __builtin_amdgcn_mfma_f32_16x16x32_bf16(A,B,C,0,0,0)
#define MFMA32(A,B,C) __builtin_amdgcn_mfma_f32_32x32x16_bf16(A,B,C,0,0,0)

#define NTOK 98
#define SROW 136
#define SCALE 0.17677669529663687f

__device__ __forceinline__ unsigned short bfu(float f) {
  union { float f; unsigned u; } un; un.f = f;
  unsigned r = un.u + 0x7FFFu + ((un.u >> 16) & 1u);
  return (unsigned short)(r >> 16);
}
__device__ __forceinline__ unsigned cvtpk(float a, float b) {
  unsigned r;
  asm("v_cvt_pk_bf16_f32 %0, %1, %2" : "=v"(r) : "v"(a), "v"(b));
  return r;
}

__global__ void prep_kernel(const float* __restrict__ qkv_w,
                            const float* __restrict__ proj_w,
                            const float* __restrict__ bias_table,
                            const int* __restrict__ rel_index,
                            const float* __restrict__ mask,
                            unsigned short* __restrict__ wq,
                            unsigned short* __restrict__ wp,
                            float* __restrict__ bsmall,
                            float* __restrict__ bm, int use_bm) {
  const int T1 = 384*128, T2 = T1 + 128*128;
  const int TS = 4*128*112;            // 57,344
  const int T3 = T2 + TS;
  const int TB = 64*4*128*112;         // 3,670,016
  const int total = T3 + (use_bm ? TB : 0);
  for (int idx = blockIdx.x*blockDim.x + threadIdx.x; idx < total;
       idx += gridDim.x*blockDim.x) {
    if (idx < T1)      wq[idx] = bfu(qkv_w[idx]);
    else if (idx < T2) wp[idx - T1] = bfu(proj_w[idx - T1]);
    else if (idx < T3) {
      int t = idx - T2;
      int m = t % 112, n = (t/112) & 127, h = t / (112*128);
      float v;
      if (m >= NTOK)      v = -1e30f;
      else if (n >= NTOK) v = 0.f;
      else                v = bias_table[rel_index[n*98+m]*4 + h];
      bsmall[t] = v;
    } else {
      int t = idx - T3;
      int m = t % 112; int r = t / 112;
      int n = r & 127; r >>= 7;
      int h = r & 3;   int w = r >> 2;
      float v;
      if (m >= NTOK)      v = -1e30f;
      else if (n >= NTOK) v = 0.f;
      else v = bias_table[rel_index[n*98+m]*4 + h] + mask[(size_t)w*9604 + n*98 + m];
      bm[t] = v;
    }
  }
}

template<int USE_BM>
__launch_bounds__(1024, 1)
__global__ void wattn_kernel(const float* __restrict__ x,
                             const float* __restrict__ mask,
                             const float* __restrict__ proj_b,
                             const unsigned short* __restrict__ wqkv,
                             const unsigned short* __restrict__ wproj,
                             const float* __restrict__ bsmall,
                             const float* __restrict__ bm,
                             float* __restrict__ out) {
  // 4 x 128x136 bf16 = 139,264 B LDS; 1024 thr = 16 waves -> 4 waves/SIMD.
  __shared__ unsigned short xb[128*SROW];   // x (bf16), reused as attn-out [n][d]
  __shared__ unsigned short qb[128*SROW];   // q pre-scaled [n][d]
  __shared__ unsigned short kb[128*SROW];   // k [m][d]
  __shared__ unsigned short vt[128*SROW];   // V^T [d][n]

  const int b = blockIdx.x, tid = threadIdx.x;
  const int wid = tid >> 6, lane = tid & 63;
  const int g = lane >> 4, c = lane & 15;

  // zero pads: xb rows 98..111 (x input pad), qb/kb rows 112..127 (attn 32-tile pad)
  for (int i = tid; i < 14*SROW; i += 1024) xb[98*SROW + i] = 0;
  for (int i = tid; i < 16*SROW; i += 1024) { qb[112*SROW + i] = 0; kb[112*SROW + i] = 0; }

  // ---- x -> LDS bf16 ----
  const float* xp = x + (size_t)b * (NTOK*128);
  for (int i = tid; i < (NTOK*128)/4; i += 1024) {
    float4 v4 = ((const float4*)xp)[i];
    int e = i*4, n = e >> 7, cc = e & 127;
    u32x2 u; u[0] = cvtpk(v4.x, v4.y); u[1] = cvtpk(v4.z, v4.w);
    *(u32x2*)&xb[n*SROW + cc] = u;
  }
  __syncthreads();

  // ---- QKV: 48 half-tile tasks over 16 waves (3 each) ----
  for (int k3 = 0; k3 < 3; ++k3) {
    const int u = wid + 16*k3;          // 0..47
    const int ot = u >> 1, half = u & 1;
    const int ib = half ? 4 : 0, ni = half ? 3 : 4;
    if (ot < 16) {                      // q (0-7) / k (8-15), operand-swapped
      const unsigned short* wptr = wqkv + (size_t)(ot*16 + c)*128;
      f4 acc[4] = {};
      #pragma unroll
      for (int kk = 0; kk < 4; ++kk) {
        bf8 wf = *(const bf8*)(wptr + kk*32 + g*8);
        #pragma unroll
        for (int i = 0; i < 4; ++i) if (i < ni) {
          bf8 xf = *(const bf8*)(&xb[((ib+i)*16 + c)*SROW + kk*32 + g*8]);
          acc[i] = MFMA16(wf, xf, acc[i]);   // D[o'][n']
        }
      }
      unsigned short* dst = (ot < 8) ? qb : kb;
      const int col = (ot & 7)*16 + g*4;
      const float sc = (ot < 8) ? SCALE : 1.f;
      #pragma unroll
      for (int i = 0; i < 4; ++i) if (i < ni) {
        u32x2 uu;
        uu[0] = cvtpk(acc[i][0]*sc, acc[i][1]*sc);
        uu[1] = cvtpk(acc[i][2]*sc, acc[i][3]*sc);
        *(u32x2*)&dst[((ib+i)*16 + c)*SROW + col] = uu;
      }
    } else {                            // v tiles -> V^T
      const int ov = ot - 16;
      const unsigned short* wptr = wqkv + (size_t)(256 + ov*16 + c)*128;
      f4 acc[4] = {};
      #pragma unroll
      for (int kk = 0; kk < 4; ++kk) {
        bf8 wf = *(const bf8*)(wptr + kk*32 + g*8);
        #pragma unroll
        for (int i = 0; i < 4; ++i) if (i < ni) {
          bf8 xf = *(const bf8*)(&xb[((ib+i)*16 + c)*SROW + kk*32 + g*8]);
          acc[i] = MFMA16(xf, wf, acc[i]);   // D[n'][o']
        }
      }
      #pragma unroll
      for (int i = 0; i < 4; ++i) if (i < ni) {
        u32x2 uu;
        uu[0] = cvtpk(acc[i][0], acc[i][1]);
        uu[1] = cvtpk(acc[i][2], acc[i][3]);
        *(u32x2*)&vt[(ov*16 + c)*SROW + (ib+i)*16 + g*4] = uu;
      }
    }
  }
  __syncthreads();

  // ---- attention: 16 tasks (4 heads x 4 n-tiles of 32), 1 per wave, 32x32 MFMA ----
  {
    const int hh = wid & 3, i32 = wid >> 2;
    const int l31 = lane & 31, hl = lane >> 5;
    const int n = i32*32 + l31;         // query row (column of S^T / out^T)

    f16v sj[4];
    const float* bmp = USE_BM ? (bm + ((size_t)((b & 63)*4 + hh)*128 + n)*112)
                              : (bsmall + ((size_t)hh*128 + n)*112);
    #pragma unroll
    for (int j = 0; j < 4; ++j)
      #pragma unroll
      for (int a = 0; a < 4; ++a) {
        f4 t;
        if (j == 3 && a >= 2) t = (f4){-1e30f, -1e30f, -1e30f, -1e30f};
        else t = *(const f4*)(bmp + j*32 + a*8 + hl*4);
        sj[j][4*a+0] = t[0]; sj[j][4*a+1] = t[1];
        sj[j][4*a+2] = t[2]; sj[j][4*a+3] = t[3];
      }
    if (!USE_BM && n < NTOK) {          // slow fallback: add mask scalars
      const float* mw = mask + (size_t)(b & 63)*9604 + n*98;
      #pragma unroll
      for (int j = 0; j < 4; ++j)
        #pragma unroll
        for (int a = 0; a < 4; ++a) {
          if (j == 3 && a >= 2) continue;
          #pragma unroll
          for (int bb = 0; bb < 4; ++bb) {
            int m = j*32 + a*8 + hl*4 + bb;
            if (m < NTOK) sj[j][4*a+bb] += mw[m];
          }
        }
    }
    // QK^T: S^T[m][n], 8 MFMAs
    #pragma unroll
    for (int kd = 0; kd < 2; ++kd) {
      bf8 qf = *(const bf8*)(&qb[n*SROW + hh*32 + kd*16 + hl*8]);
      #pragma unroll
      for (int j = 0; j < 4; ++j) {
        bf8 kf = *(const bf8*)(&kb[(j*32 + l31)*SROW + hh*32 + kd*16 + hl*8]);
        sj[j] = MFMA32(kf, qf, sj[j]);
      }
    }
    // softmax (no max-sub: bounded scores; masked -> exp(-1e30)=0)
    float sum = 0.f;
    #pragma unroll
    for (int j = 0; j < 4; ++j)
      #pragma unroll
      for (int r = 0; r < 16; ++r) { float e = __expf(sj[j][r]); sj[j][r] = e; sum += e; }
    sum += __shfl_xor(sum, 32);
    const float inv = 1.f / sum;        // folded into PV epilogue
    // pack P (unnormalized) to bf16 pairs: P2[j][a] = run m0 = 32j+8a+4hl
    unsigned P2[4][4][2];
    #pragma unroll
    for (int j = 0; j < 4; ++j)
      #pragma unroll
      for (int a = 0; a < 4; ++a) {
        P2[j][a][0] = cvtpk(sj[j][4*a+0], sj[j][4*a+1]);
        P2[j][a][1] = cvtpk(sj[j][4*a+2], sj[j][4*a+3]);
      }
    // PV: out^T[d][n], 7 MFMAs (m 112..127 has P=0, skipped)
    f16v acc = {0.f,0.f,0.f,0.f,0.f,0.f,0.f,0.f,0.f,0.f,0.f,0.f,0.f,0.f,0.f,0.f};
    #pragma unroll
    for (int km = 0; km < 7; ++km) {
      const int j = km >> 1, a0 = 2*(km & 1);
      bf8 vf = *(const bf8*)(&vt[(hh*32 + l31)*SROW + km*16 + hl*8]);
      unsigned o0 = P2[j][a0][0],   o1 = P2[j][a0][1];
      unsigned o2 = P2[j][a0+1][0], o3 = P2[j][a0+1][1];
      unsigned s0 = __shfl_xor(o0, 32), s1 = __shfl_xor(o1, 32);
      unsigned s2 = __shfl_xor(o2, 32), s3 = __shfl_xor(o3, 32);
      u32x4 pw;
      pw[0] = hl ? s2 : o0;  pw[1] = hl ? s3 : o1;
      pw[2] = hl ? o2 : s0;  pw[3] = hl ? o3 : s1;
      acc = MFMA32(vf, *(bf8*)&pw, acc);
    }
    #pragma unroll
    for (int a = 0; a < 4; ++a) {
      u32x2 uu;
      uu[0] = cvtpk(acc[4*a+0]*inv, acc[4*a+1]*inv);
      uu[1] = cvtpk(acc[4*a+2]*inv, acc[4*a+3]*inv);
      *(u32x2*)&xb[n*SROW + hh*32 + a*8 + hl*4] = uu;
    }
  }
  __syncthreads();

  // ---- proj: 56 tasks over 16 waves ----
  for (int k3 = 0; k3 < 4; ++k3) {
    const int t = wid + 16*k3;
    if (t < 56) {
      const int i = t >> 3, ot = t & 7;
      const unsigned short* wptr = wproj + (size_t)(ot*16 + c)*128;
      f4 acc = {0.f, 0.f, 0.f, 0.f};
      #pragma unroll
      for (int kk = 0; kk < 4; ++kk) {
        bf8 wf = *(const bf8*)(wptr + kk*32 + g*8);
        bf8 xf = *(const bf8*)(&xb[(i*16 + c)*SROW + kk*32 + g*8]);
        acc = MFMA16(wf, xf, acc);       // D[o'][n']
      }
      const int n2 = i*16 + c;
      if (n2 < NTOK) {
        f4 pb4 = *(const f4*)(proj_b + ot*16 + g*4);
        f4 o4 = {acc[0]+pb4[0], acc[1]+pb4[1], acc[2]+pb4[2], acc[3]+pb4[3]};
        *(f4*)(out + (size_t)b*(NTOK*128) + n2*128 + ot*16 + g*4) = o4;
      }
    }
  }
}

extern "C" void kernel_launch(void* const* d_in, const int* in_sizes, int n_in,
                              void* d_out, int out_size, void* d_ws, size_t ws_size,
                              hipStream_t stream) {
  const float* x          = (const float*)d_in[0];
  const float* mask       = (const float*)d_in[1];
  const float* qkv_w      = (const float*)d_in[2];
  const float* proj_w     = (const float*)d_in[3];
  const float* proj_b     = (const float*)d_in[4];
  const float* bias_table = (const float*)d_in[5];
  const int*   rel_index  = (const int*)d_in[6];

  // ws layout: wqkv bf16 (98,304 B) | wproj bf16 (32,768 B) @131,072 |
  //            bsmall fp32 229,376 B @131,072 | bm fp32 14,680,064 B @360,448
  unsigned short* wq = (unsigned short*)d_ws;
  unsigned short* wp = wq + 384*128;
  float* bsmall = (float*)((char*)d_ws + 131072);
  float* bm     = (float*)((char*)d_ws + 360448);

  const size_t need = 360448u + (size_t)64*4*128*112*4;  // ~14.35 MB
  const int use_bm = (ws_size >= need) ? 1 : 0;

  prep_kernel<<<2048, 256, 0, stream>>>(qkv_w, proj_w, bias_table, rel_index, mask,
                                        wq, wp, bsmall, bm, use_bm);
  if (use_bm)
    wattn_kernel<1><<<4096, 1024, 0, stream>>>(x, mask, proj_b, wq, wp, bsmall, bm,
                                               (float*)d_out);
  else
    wattn_kernel<0><<<4096, 1024, 0, stream>>>(x, mask, proj_b, wq, wp, bsmall, bm,
                                               (float*)d_out);
}